// Round 3
// baseline (62.937 us; speedup 1.0000x reference)
//
#include <hip/hip_runtime.h>
#include <math.h>

#define BB 16
#define PP 16384
#define TT 64
#define CC 85
#define NUMCLS 80
#define WAVES 4
#define WPW 64                        // preds per wave in pass1
#define PRED_PER_BLK (WAVES * WPW)    // 256
#define BLKS_PER_B (PP / PRED_PER_BLK)// 64
#define WSLOTS (PP / WPW)             // 256 wave slots per batch

// ws layout (floats):
// [0 .. 524287]        cand float2[16*64*256]  (val, idx-bits)
// [524288 .. 525311]   conf softplus partial per pass1 block (1024)
// [525312 .. 526335]   box loss per (b,t)
// [526336 .. 527359]   cls loss per (b,t)
// [527360 .. 528383]   matched idx (int) per (b,t)

__global__ __launch_bounds__(256) void pass1_kernel(const float* __restrict__ raw,
                                                    const float* __restrict__ tgt,
                                                    float2* __restrict__ cand,
                                                    float* __restrict__ conf_part) {
#pragma clang fp contract(off)
    int b     = blockIdx.x / BLKS_PER_B;
    int chunk = blockIdx.x % BLKS_PER_B;
    int wave  = threadIdx.x >> 6;
    int lane  = threadIdx.x & 63;
    int p0    = chunk * PRED_PER_BLK + wave * WPW;

    const float* base = raw + (size_t)b * PP * CC;

    __shared__ float sp[WAVES][5][WPW];   // per-wave SoA: x1,y1,x2,y2,area
    __shared__ float cw[WAVES];

    // Stage own row (per-wave, no block sync needed) + softplus(conf).
    float conf_acc;
    {
        const float* pr = base + (size_t)(p0 + lane) * CC;
        float px1 = pr[0], py1 = pr[1], px2 = pr[2], py2 = pr[3], c = pr[4];
        sp[wave][0][lane] = px1;
        sp[wave][1][lane] = py1;
        sp[wave][2][lane] = px2;
        sp[wave][3][lane] = py2;
        sp[wave][4][lane] = (px2 - px1) * (py2 - py1);
        conf_acc = fmaxf(c, 0.0f) + log1pf(expf(-fabsf(c)));
    }

    // Lane owns target `lane`.
    const float* trow = tgt + (size_t)(b * TT + lane) * 5;
    float tx1 = trow[0], ty1 = trow[1], tx2 = trow[2], ty2 = trow[3];
    float area_t = (tx2 - tx1) * (ty2 - ty1);

    float best = -1.0f;
    int bidx = 0;
#pragma unroll 4
    for (int j = 0; j < WPW; ++j) {
        float px1 = sp[wave][0][j];
        float py1 = sp[wave][1][j];
        float px2 = sp[wave][2][j];
        float py2 = sp[wave][3][j];
        float ap  = sp[wave][4][j];
        float x1 = fmaxf(px1, tx1), y1 = fmaxf(py1, ty1);
        float x2 = fminf(px2, tx2), y2 = fminf(py2, ty2);
        float w = x2 - x1, h = y2 - y1;
        float inter = w * h;
        bool valid = (w > 0.0f) && (h > 0.0f);
        float uni = (ap + area_t) - inter;
        float iou = (valid && (uni > 0.0f)) ? (inter / uni) : 0.0f;
        if (iou > best) { best = iou; bidx = p0 + j; }  // ascending j -> first max kept
    }

    int slot = chunk * WAVES + wave;   // monotone in pred index
    cand[(size_t)(b * TT + lane) * WSLOTS + slot] = make_float2(best, __int_as_float(bidx));

    // conf softplus: wave reduce then block combine.
    for (int m = 32; m > 0; m >>= 1) conf_acc += __shfl_xor(conf_acc, m);
    if (lane == 0) cw[wave] = conf_acc;
    __syncthreads();
    if (threadIdx.x == 0) conf_part[blockIdx.x] = (cw[0] + cw[1]) + (cw[2] + cw[3]);
}

__global__ __launch_bounds__(256) void pass2_kernel(const float* __restrict__ raw,
                                                    const float* __restrict__ tgt,
                                                    const float2* __restrict__ cand,
                                                    float* __restrict__ box_out,
                                                    float* __restrict__ cls_out,
                                                    int* __restrict__ matched) {
#pragma clang fp contract(off)
    int b    = blockIdx.x >> 2;
    int tg   = blockIdx.x & 3;
    int wave = threadIdx.x >> 6;
    int lane = threadIdx.x & 63;

    for (int it = 0; it < 4; ++it) {
        int t  = tg * 16 + wave * 4 + it;
        int bt = b * TT + t;

        const float2* cb = cand + (size_t)bt * WSLOTS;
        float v = -2.0f;
        int idx = 0x7fffffff;
        for (int k = lane; k < WSLOTS; k += 64) {
            float2 c2 = cb[k];
            int i2 = __float_as_int(c2.y);
            if (c2.x > v || (c2.x == v && i2 < idx)) { v = c2.x; idx = i2; }
        }
        for (int m = 1; m < 64; m <<= 1) {
            float ov = __shfl_xor(v, m);
            int   oi = __shfl_xor(idx, m);
            if (ov > v || (ov == v && oi < idx)) { v = ov; idx = oi; }
        }
        // all lanes now agree on idx
        const float* prow = raw + ((size_t)b * PP + idx) * CC;
        float l0 = prow[5 + lane];
        float l1 = (lane < 16) ? prow[69 + lane] : -INFINITY;
        float mx = fmaxf(l0, l1);
        for (int m = 1; m < 64; m <<= 1) mx = fmaxf(mx, __shfl_xor(mx, m));
        float e = expf(l0 - mx) + ((lane < 16) ? expf(l1 - mx) : 0.0f);
        for (int m = 1; m < 64; m <<= 1) e += __shfl_xor(e, m);

        if (lane == 0) {
            const float* trow = tgt + (size_t)bt * 5;
            int tcls = (int)trow[4];
            cls_out[bt] = (mx + logf(e)) - prow[5 + tcls];
            float s = 0.0f;
            for (int k2 = 0; k2 < 4; ++k2) {
                float d = fabsf(prow[k2] - trow[k2]);
                s += (d < 1.0f) ? 0.5f * d * d : (d - 0.5f);
            }
            box_out[bt] = s;
            matched[bt] = idx;
        }
    }
}

__global__ __launch_bounds__(256) void finalize_kernel(const float* __restrict__ raw,
                                                       const float* __restrict__ conf_part,
                                                       const float* __restrict__ box_p,
                                                       const float* __restrict__ cls_p,
                                                       const int* __restrict__ matched,
                                                       float* __restrict__ out) {
    __shared__ int sm[BB * TT];
    __shared__ float red[256];
    int tid = threadIdx.x;
    for (int i = tid; i < BB * TT; i += 256) sm[i] = matched[i];
    __syncthreads();

    float acc = 0.0f;
    for (int i = tid; i < BB * TT; i += 256) {
        int bb = i >> 6;
        int m = sm[i];
        bool first = true;
        for (int t2 = bb * 64; t2 < i; ++t2)
            if (sm[t2] == m) { first = false; break; }
        float sub = first ? raw[((size_t)bb * PP + m) * CC + 4] : 0.0f;
        acc += 5.0f * box_p[i] + cls_p[i] - sub;
    }
    for (int i = tid; i < 1024; i += 256) acc += conf_part[i];

    red[tid] = acc;
    __syncthreads();
    for (int s = 128; s > 0; s >>= 1) {
        if (tid < s) red[tid] += red[tid + s];
        __syncthreads();
    }
    if (tid == 0) out[0] = red[0] / (float)BB;
}

extern "C" void kernel_launch(void* const* d_in, const int* in_sizes, int n_in,
                              void* d_out, int out_size, void* d_ws, size_t ws_size,
                              hipStream_t stream) {
    const float* raw = (const float*)d_in[0];
    const float* tgt = (const float*)d_in[1];
    float* out = (float*)d_out;
    float* wsf = (float*)d_ws;

    float2* cand    = (float2*)wsf;                 // 262144 float2
    float*  conf_p  = wsf + 524288;                 // 1024
    float*  box_p   = wsf + 525312;                 // 1024
    float*  cls_p   = wsf + 526336;                 // 1024
    int*    match   = (int*)(wsf + 527360);         // 1024

    pass1_kernel<<<BB * BLKS_PER_B, 256, 0, stream>>>(raw, tgt, cand, conf_p);
    pass2_kernel<<<64, 256, 0, stream>>>(raw, tgt, cand, box_p, cls_p, match);
    finalize_kernel<<<1, 256, 0, stream>>>(raw, conf_p, box_p, cls_p, match, out);
}